// Round 11
// baseline (122.208 us; speedup 1.0000x reference)
//
#include <hip/hip_runtime.h>
#include <hip/hip_bf16.h>
#include <stdint.h>

#define NG 16
#define NN 2048
#define DD 512
#define NROW (NG * NN)   // 32768
#define NT8 8            // 2048 / 256
#define NPAIR8 36        // 8*9/2
#define NXCD 8

typedef __attribute__((ext_vector_type(8))) short short8;
typedef __attribute__((ext_vector_type(4))) float f32x4;

__device__ inline unsigned short f2bf(float f) {
  union { float f; unsigned int u; } c;
  c.f = f;
  unsigned int x = c.u;
  unsigned int r = (x + 0x7fffu + ((x >> 16) & 1u)) >> 16;  // RNE
  return (unsigned short)r;
}

__device__ inline void gload_lds16(const void* g, void* l) {
  __builtin_amdgcn_global_load_lds(
      (const __attribute__((address_space(1))) void*)g,
      (__attribute__((address_space(3))) void*)l, 16, 0, 0);
}

__device__ inline void barrier_lds_only() {
  asm volatile("s_waitcnt lgkmcnt(0)" ::: "memory");
  __builtin_amdgcn_s_barrier();
}

// ---------------- prep: sq[row] = ||h_row||^2 (f32), optional bf16 cast ----------------
template <bool WRITE_BF>
__global__ __launch_bounds__(256) void prep_kernel(const float* __restrict__ h,
                                                   unsigned short* __restrict__ hbf,
                                                   float* __restrict__ sq) {
  const int row = blockIdx.x * 4 + (threadIdx.x >> 6);
  const int lane = threadIdx.x & 63;
  const float* hr = h + (size_t)row * DD;
  float4 v0 = ((const float4*)hr)[lane * 2];
  float4 v1 = ((const float4*)hr)[lane * 2 + 1];
  float s = v0.x * v0.x + v0.y * v0.y + v0.z * v0.z + v0.w * v0.w +
            v1.x * v1.x + v1.y * v1.y + v1.z * v1.z + v1.w * v1.w;
  if (WRITE_BF) {
    union { unsigned short us[8]; uint4 u4; } pk;
    pk.us[0] = f2bf(v0.x); pk.us[1] = f2bf(v0.y);
    pk.us[2] = f2bf(v0.z); pk.us[3] = f2bf(v0.w);
    pk.us[4] = f2bf(v1.x); pk.us[5] = f2bf(v1.y);
    pk.us[6] = f2bf(v1.z); pk.us[7] = f2bf(v1.w);
    ((uint4*)(hbf + (size_t)row * DD))[lane] = pk.u4;
  }
#pragma unroll
  for (int off = 32; off > 0; off >>= 1) s += __shfl_xor(s, off, 64);
  if (lane == 0) sq[row] = s;
}

// ---------------- batched Gram GEMM, 256x256 tri tiles ----------------
// 512 threads = 8 waves (2 x 4): wave (wr,wc) owns rows wr*128+[0,128),
// cols wc*64+[0,64) = 8x4 frags of 16x16x32 bf16 MFMA. BK=64, LDS 64 KB.
// Tri grid (bi<=bj in 8x8 of 256-tiles); mirror-symmetric write covers both
// [J,I] and (offdiag) [I,J]. Epilogue stages C through the 64 KB LDS in
// 64-row chunks; EVERY global store is one wave writing 1 KB CONTIGUOUS of
// one output row (DRAM page locality — the point of 256-wide tiles).
template <bool USE_WS>
__global__ __launch_bounds__(512) void gram_kernel(const unsigned short* __restrict__ hbf,
                                                   const float* __restrict__ hf,
                                                   const float* __restrict__ sq,
                                                   float* __restrict__ out) {
  __shared__ __align__(16) char smem[65536];
  unsigned short* As = (unsigned short*)smem;            // 32 KB
  unsigned short* Bs = (unsigned short*)(smem + 32768);  // 32 KB

  const int t = threadIdx.x;
  const int lane = t & 63, wid = t >> 6;
  const int wr = wid >> 2, wc = wid & 3;
  const int l16 = lane & 15, lhi = lane >> 4;

  const int bid = blockIdx.x;
  const int xcd = bid & (NXCD - 1);
  const int slot = bid >> 3;              // 0..71
  const int gh = (slot >= NPAIR8) ? 1 : 0;
  const int g = xcd * 2 + gh;
  int p = slot - gh * NPAIR8;             // 0..35
  int bi = 0, rowlen = NT8;
  while (p >= rowlen) { p -= rowlen; ++bi; --rowlen; }
  const int bj = bi + p;

  // Convoy stagger: 2 resident blocks/CU (slots ~32 apart) get ~2.4 us offset.
  {
    const int phase = (slot >> 5) & 1;
    for (int i = 0; i < phase * 6; ++i) __builtin_amdgcn_s_sleep(15);
  }

  const size_t rowA = (size_t)g * NN + bi * 256;
  const size_t rowB = (size_t)g * NN + bj * 256;

  f32x4 acc[8][4];
#pragma unroll
  for (int m = 0; m < 8; ++m)
#pragma unroll
    for (int n = 0; n < 4; ++n) acc[m][n] = (f32x4){0.f, 0.f, 0.f, 0.f};

  for (int kt = 0; kt < DD / 64; ++kt) {
    if (USE_WS) {
      const char* Ab = (const char*)(hbf + rowA * DD + kt * 64);
      const char* Bb = (const char*)(hbf + rowB * DD + kt * 64);
#pragma unroll
      for (int r = 0; r < 4; ++r) {
        const int off = r * 8192 + t * 16;   // byte offset in 32-KB LDS tile
        const int rw = off >> 7;             // tile row (128 B per row)
        const int cb = off & 127;
        gload_lds16(Ab + (size_t)rw * (DD * 2) + cb, (char*)As + r * 8192 + wid * 1024);
        gload_lds16(Bb + (size_t)rw * (DD * 2) + cb, (char*)Bs + r * 8192 + wid * 1024);
      }
    } else {
      const float* Af = hf + rowA * DD + kt * 64;
      const float* Bf = hf + rowB * DD + kt * 64;
#pragma unroll
      for (int r = 0; r < 4; ++r) {
        const int off = r * 8192 + t * 16;
        const int rw = off >> 7;
        const int c0 = (off & 127) >> 1;  // f32 column within 64-wide slab
        float4 a0 = *(const float4*)(Af + (size_t)rw * DD + c0);
        float4 a1 = *(const float4*)(Af + (size_t)rw * DD + c0 + 4);
        float4 b0 = *(const float4*)(Bf + (size_t)rw * DD + c0);
        float4 b1 = *(const float4*)(Bf + (size_t)rw * DD + c0 + 4);
        union { unsigned short us[8]; uint4 u4; } pa, pb;
        pa.us[0] = f2bf(a0.x); pa.us[1] = f2bf(a0.y);
        pa.us[2] = f2bf(a0.z); pa.us[3] = f2bf(a0.w);
        pa.us[4] = f2bf(a1.x); pa.us[5] = f2bf(a1.y);
        pa.us[6] = f2bf(a1.z); pa.us[7] = f2bf(a1.w);
        pb.us[0] = f2bf(b0.x); pb.us[1] = f2bf(b0.y);
        pb.us[2] = f2bf(b0.z); pb.us[3] = f2bf(b0.w);
        pb.us[4] = f2bf(b1.x); pb.us[5] = f2bf(b1.y);
        pb.us[6] = f2bf(b1.z); pb.us[7] = f2bf(b1.w);
        *(uint4*)((char*)As + off) = pa.u4;
        *(uint4*)((char*)Bs + off) = pb.u4;
      }
    }
    __syncthreads();
#pragma unroll
    for (int kk = 0; kk < 2; ++kk) {
      short8 af[8], bfr[4];
#pragma unroll
      for (int m = 0; m < 8; ++m)
        af[m] = *(const short8*)&As[(wr * 128 + m * 16 + l16) * 64 + kk * 32 + lhi * 8];
#pragma unroll
      for (int n = 0; n < 4; ++n)
        bfr[n] = *(const short8*)&Bs[(wc * 64 + n * 16 + l16) * 64 + kk * 32 + lhi * 8];
#pragma unroll
      for (int m = 0; m < 8; ++m)
#pragma unroll
        for (int n = 0; n < 4; ++n)
          acc[m][n] = __builtin_amdgcn_mfma_f32_16x16x32_bf16(af[m], bfr[n], acc[m][n], 0, 0, 0);
    }
    __syncthreads();  // last iter also guards Cs reuse of As/Bs
  }

  // ---------------- epilogue: val = sq_i + sq_j - 2*gram ----------------
  float sqr[8][4];
  float sqc[4];
#pragma unroll
  for (int m = 0; m < 8; ++m)
#pragma unroll
    for (int r = 0; r < 4; ++r)
      sqr[m][r] = sq[rowA + wr * 128 + m * 16 + lhi * 4 + r];
#pragma unroll
  for (int n = 0; n < 4; ++n) sqc[n] = sq[rowB + wc * 64 + n * 16 + l16];

  float* outg = out + (size_t)g * NN * NN;
  const bool offdiag = (bi != bj);

  // ---- Mirror region [J, I]: rows bj*256 + j', cols bi*256 + i'. ----
  // Chunk c: j' in [c*64, c*64+64). Cs: [jl 0..63][i' 0..255] f32 =
  // 64 rows x 1024 B; 16-B slot index phys = slot ^ (jl & 31).
#pragma unroll
  for (int c = 0; c < 4; ++c) {
    if (wc == c) {
#pragma unroll
      for (int n = 0; n < 4; ++n)
#pragma unroll
        for (int m = 0; m < 8; ++m) {
          f32x4 v;
          v.x = sqr[m][0] + sqc[n] - 2.0f * acc[m][n][0];
          v.y = sqr[m][1] + sqc[n] - 2.0f * acc[m][n][1];
          v.z = sqr[m][2] + sqc[n] - 2.0f * acc[m][n][2];
          v.w = sqr[m][3] + sqc[n] - 2.0f * acc[m][n][3];
          const int jl = n * 16 + l16;               // 0..63
          const int sl = wr * 32 + m * 4 + lhi;      // 0..63 (i'/4)
          *(f32x4*)(smem + jl * 1024 + ((sl ^ (jl & 31)) << 4)) = v;
        }
    }
    barrier_lds_only();
    {
      const int jrow0 = bj * 256 + c * 64;
#pragma unroll
      for (int k = 0; k < 8; ++k) {
        const int idx = k * 512 + t;
        const int jl = idx >> 6;          // each wave reads one 1-KB row
        const int s = idx & 63;
        f32x4 v = *(const f32x4*)(smem + jl * 1024 + ((s ^ (jl & 31)) << 4));
        __builtin_nontemporal_store(
            v, (f32x4*)&outg[(size_t)(jrow0 + jl) * NN + bi * 256 + s * 4]);
      }
    }
    barrier_lds_only();
  }

  // ---- Transposed region [I, J] (offdiag): rows bi*256 + i', cols bj*256 + j'.
  // Chunk ci: i' in [ci*64, +64). Cs: [il 0..63][j' 0..255] f32; scalar writes
  // at f32 index phys_e = j' ^ ((il & 31) << 2) (f32x4-group preserving).
  if (offdiag) {
#pragma unroll
    for (int ci = 0; ci < 4; ++ci) {
      if (wr == (ci >> 1)) {
#pragma unroll
        for (int mm = 0; mm < 4; ++mm) {
          const int m = (ci & 1) * 4 + mm;
#pragma unroll
          for (int n = 0; n < 4; ++n) {
            const int jp = wc * 64 + n * 16 + l16;   // j' 0..255
#pragma unroll
            for (int r = 0; r < 4; ++r) {
              const int il = mm * 16 + lhi * 4 + r;  // local i' 0..63
              const float val = sqr[m][r] + sqc[n] - 2.0f * acc[m][n][r];
              *(float*)(smem + il * 1024 + ((jp ^ ((il & 31) << 2)) << 2)) = val;
            }
          }
        }
      }
      barrier_lds_only();
      {
        const int irow0 = bi * 256 + ci * 64;
#pragma unroll
        for (int k = 0; k < 8; ++k) {
          const int idx = k * 512 + t;
          const int il = idx >> 6;
          const int s = idx & 63;
          f32x4 v = *(const f32x4*)(smem + il * 1024 + ((s ^ (il & 31)) << 4));
          __builtin_nontemporal_store(
              v, (f32x4*)&outg[(size_t)(irow0 + il) * NN + bj * 256 + s * 4]);
        }
      }
      if (ci < 3) barrier_lds_only();
    }
  }
}

extern "C" void kernel_launch(void* const* d_in, const int* in_sizes, int n_in,
                              void* d_out, int out_size, void* d_ws, size_t ws_size,
                              hipStream_t stream) {
  const float* h = (const float*)d_in[0];
  float* out = (float*)d_out;

  float* sq = (float*)d_ws;                                   // 32768 f32 = 128 KB
  unsigned short* hbf = (unsigned short*)((char*)d_ws + NROW * 4);  // 32 MB bf16
  const size_t need_ws = (size_t)NROW * 4 + (size_t)NROW * DD * 2;
  const bool use_ws = ws_size >= need_ws;

  if (use_ws) {
    prep_kernel<true><<<NROW / 4, 256, 0, stream>>>(h, hbf, sq);
    gram_kernel<true><<<NG * NPAIR8, 512, 0, stream>>>(hbf, nullptr, sq, out);
  } else {
    prep_kernel<false><<<NROW / 4, 256, 0, stream>>>(h, nullptr, sq);
    gram_kernel<false><<<NG * NPAIR8, 512, 0, stream>>>(nullptr, h, sq, out);
  }
}

// Round 12
// 110.022 us; speedup vs baseline: 1.1108x; 1.1108x over previous
//
#include <hip/hip_runtime.h>
#include <hip/hip_bf16.h>
#include <stdint.h>

#define NG 16
#define NN 2048
#define DD 512
#define NROW (NG * NN)   // 32768
#define NTILE 16         // 2048 / 128
#define NPAIR 136        // NTILE*(NTILE+1)/2
#define NXCD 8

typedef __attribute__((ext_vector_type(8))) short short8;
typedef __attribute__((ext_vector_type(4))) float f32x4;

__device__ inline unsigned short f2bf(float f) {
  union { float f; unsigned int u; } c;
  c.f = f;
  unsigned int x = c.u;
  unsigned int r = (x + 0x7fffu + ((x >> 16) & 1u)) >> 16;  // RNE
  return (unsigned short)r;
}

__device__ inline void gload_lds16(const void* g, void* l) {
  __builtin_amdgcn_global_load_lds(
      (const __attribute__((address_space(1))) void*)g,
      (__attribute__((address_space(3))) void*)l, 16, 0, 0);
}

__device__ inline void barrier_lds_only() {
  asm volatile("s_waitcnt lgkmcnt(0)" ::: "memory");
  __builtin_amdgcn_s_barrier();
}

// ---------------- prep: sq[row] = ||h_row||^2 (f32), optional bf16 cast ----------------
template <bool WRITE_BF>
__global__ __launch_bounds__(256) void prep_kernel(const float* __restrict__ h,
                                                   unsigned short* __restrict__ hbf,
                                                   float* __restrict__ sq) {
  const int row = blockIdx.x * 4 + (threadIdx.x >> 6);
  const int lane = threadIdx.x & 63;
  const float* hr = h + (size_t)row * DD;
  float4 v0 = ((const float4*)hr)[lane * 2];
  float4 v1 = ((const float4*)hr)[lane * 2 + 1];
  float s = v0.x * v0.x + v0.y * v0.y + v0.z * v0.z + v0.w * v0.w +
            v1.x * v1.x + v1.y * v1.y + v1.z * v1.z + v1.w * v1.w;
  if (WRITE_BF) {
    union { unsigned short us[8]; uint4 u4; } pk;
    pk.us[0] = f2bf(v0.x); pk.us[1] = f2bf(v0.y);
    pk.us[2] = f2bf(v0.z); pk.us[3] = f2bf(v0.w);
    pk.us[4] = f2bf(v1.x); pk.us[5] = f2bf(v1.y);
    pk.us[6] = f2bf(v1.z); pk.us[7] = f2bf(v1.w);
    ((uint4*)(hbf + (size_t)row * DD))[lane] = pk.u4;
  }
#pragma unroll
  for (int off = 32; off > 0; off >>= 1) s += __shfl_xor(s, off, 64);
  if (lane == 0) sq[row] = s;
}

// ---------------- batched Gram GEMM, 16-KB LDS footprint (8 blocks/CU) ----------------
// Tri grid (bi<=bj), 128x128 tile, BK=32, 4 waves (2x2), 16x16x32 bf16 MFMA.
// Occupancy is the lever: 16 KB LDS -> 8 blocks/CU (wave cap), so store-phase
// back-pressure in some blocks overlaps K-loop compute in others.
// Epilogue: 16-KB quarter-chunks (32 rows x 512 B), XOR-swizzled; all global
// stores are nt f32x4 full-line; barriers lgkm-only.
template <bool USE_WS>
__global__ __launch_bounds__(256) void gram_kernel(const unsigned short* __restrict__ hbf,
                                                   const float* __restrict__ hf,
                                                   const float* __restrict__ sq,
                                                   float* __restrict__ out) {
  __shared__ __align__(16) char smem[16384];
  unsigned short* As = (unsigned short*)smem;           // 8 KB (K-loop)
  unsigned short* Bs = (unsigned short*)(smem + 8192);  // 8 KB (K-loop)

  const int t = threadIdx.x;
  const int lane = t & 63, wid = t >> 6;
  const int wr = wid >> 1, wc = wid & 1;
  const int l16 = lane & 15, lhi = lane >> 4;

  const int bid = blockIdx.x;
  const int xcd = bid & (NXCD - 1);
  const int slot = bid >> 3;              // 0..271
  const int gh = (slot >= NPAIR) ? 1 : 0;
  const int g = xcd * 2 + gh;
  int p = slot - gh * NPAIR;              // 0..135
  int bi = 0, rowlen = NTILE;
  while (p >= rowlen) { p -= rowlen; ++bi; --rowlen; }
  const int bj = bi + p;

  // Convoy stagger: 8 resident blocks/CU (slots 32 apart) -> 8 phases x ~1.2us.
  {
    const int phase = (slot >> 5) & 7;
    for (int i = 0; i < phase * 3; ++i) __builtin_amdgcn_s_sleep(15);
  }

  const size_t rowA = (size_t)g * NN + bi * 128;
  const size_t rowB = (size_t)g * NN + bj * 128;

  f32x4 acc[4][4];
#pragma unroll
  for (int m = 0; m < 4; ++m)
#pragma unroll
    for (int n = 0; n < 4; ++n) acc[m][n] = (f32x4){0.f, 0.f, 0.f, 0.f};

  for (int kt = 0; kt < DD / 32; ++kt) {
    if (USE_WS) {
      const char* Ab = (const char*)(hbf + rowA * DD + kt * 32);
      const char* Bb = (const char*)(hbf + rowB * DD + kt * 32);
#pragma unroll
      for (int r = 0; r < 2; ++r) {
        const int off = r * 4096 + t * 16;   // byte offset in 8-KB LDS tile
        const int rw = off >> 6;             // tile row (64 B per row)
        const int cb = off & 63;
        gload_lds16(Ab + (size_t)rw * (DD * 2) + cb, (char*)As + r * 4096 + wid * 1024);
        gload_lds16(Bb + (size_t)rw * (DD * 2) + cb, (char*)Bs + r * 4096 + wid * 1024);
      }
    } else {
      const float* Af = hf + rowA * DD + kt * 32;
      const float* Bf = hf + rowB * DD + kt * 32;
#pragma unroll
      for (int r = 0; r < 2; ++r) {
        const int off = r * 4096 + t * 16;
        const int rw = off >> 6;
        const int c0 = (off & 63) >> 1;  // f32 column
        float4 a0 = *(const float4*)(Af + (size_t)rw * DD + c0);
        float4 a1 = *(const float4*)(Af + (size_t)rw * DD + c0 + 4);
        float4 b0 = *(const float4*)(Bf + (size_t)rw * DD + c0);
        float4 b1 = *(const float4*)(Bf + (size_t)rw * DD + c0 + 4);
        union { unsigned short us[8]; uint4 u4; } pa, pb;
        pa.us[0] = f2bf(a0.x); pa.us[1] = f2bf(a0.y);
        pa.us[2] = f2bf(a0.z); pa.us[3] = f2bf(a0.w);
        pa.us[4] = f2bf(a1.x); pa.us[5] = f2bf(a1.y);
        pa.us[6] = f2bf(a1.z); pa.us[7] = f2bf(a1.w);
        pb.us[0] = f2bf(b0.x); pb.us[1] = f2bf(b0.y);
        pb.us[2] = f2bf(b0.z); pb.us[3] = f2bf(b0.w);
        pb.us[4] = f2bf(b1.x); pb.us[5] = f2bf(b1.y);
        pb.us[6] = f2bf(b1.z); pb.us[7] = f2bf(b1.w);
        *(uint4*)((char*)As + off) = pa.u4;
        *(uint4*)((char*)Bs + off) = pb.u4;
      }
    }
    __syncthreads();
    {
      short8 af[4], bfr[4];
#pragma unroll
      for (int m = 0; m < 4; ++m)
        af[m] = *(const short8*)&As[(wr * 64 + m * 16 + l16) * 32 + lhi * 8];
#pragma unroll
      for (int n = 0; n < 4; ++n)
        bfr[n] = *(const short8*)&Bs[(wc * 64 + n * 16 + l16) * 32 + lhi * 8];
#pragma unroll
      for (int m = 0; m < 4; ++m)
#pragma unroll
        for (int n = 0; n < 4; ++n)
          acc[m][n] = __builtin_amdgcn_mfma_f32_16x16x32_bf16(af[m], bfr[n], acc[m][n], 0, 0, 0);
    }
    __syncthreads();  // last iter also guards Cs reuse of As/Bs
  }

  // ---------------- epilogue: val = sq_i + sq_j - 2*gram ----------------
  float sqr[4][4];
  float sqc[4];
#pragma unroll
  for (int m = 0; m < 4; ++m)
#pragma unroll
    for (int r = 0; r < 4; ++r)
      sqr[m][r] = sq[rowA + wr * 64 + m * 16 + lhi * 4 + r];
#pragma unroll
  for (int n = 0; n < 4; ++n) sqc[n] = sq[rowB + wc * 64 + n * 16 + l16];

  float* outg = out + (size_t)g * NN * NN;
  const bool offdiag = (bi != bj);

  // ---- Mirror region [J,I] in 4 quarter-chunks: j' in [32q, 32q+32). ----
  // Cs quarter: [jrow 0..31][i' 0..127] f32 = 32 x 512 B = 16 KB;
  // phys 16-B slot = slot ^ jrow.
#pragma unroll
  for (int q = 0; q < 4; ++q) {
    if (wc == (q >> 1)) {
#pragma unroll
      for (int nn2 = 0; nn2 < 2; ++nn2) {
        const int n = (q & 1) * 2 + nn2;
        const int jrow = n * 16 + l16 - (q & 1) * 32;  // 0..31
#pragma unroll
        for (int m = 0; m < 4; ++m) {
          f32x4 v;
          v.x = sqr[m][0] + sqc[n] - 2.0f * acc[m][n][0];
          v.y = sqr[m][1] + sqc[n] - 2.0f * acc[m][n][1];
          v.z = sqr[m][2] + sqc[n] - 2.0f * acc[m][n][2];
          v.w = sqr[m][3] + sqc[n] - 2.0f * acc[m][n][3];
          const int sl = wr * 16 + m * 4 + lhi;        // i'/4: 0..31
          *(f32x4*)(smem + jrow * 512 + ((sl ^ jrow) << 4)) = v;
        }
      }
    }
    barrier_lds_only();
    {
      const int jrow0 = bj * 128 + q * 32;
#pragma unroll
      for (int k = 0; k < 4; ++k) {
        const int idx = k * 256 + t;
        const int jl = idx >> 5;       // 0..31
        const int s = idx & 31;
        f32x4 v = *(const f32x4*)(smem + jl * 512 + ((s ^ jl) << 4));
        __builtin_nontemporal_store(
            v, (f32x4*)&outg[(size_t)(jrow0 + jl) * NN + bi * 128 + s * 4]);
      }
    }
    barrier_lds_only();
  }

  // ---- Transposed region [I,J] (offdiag), 4 quarter-chunks: i' in [32qi,+32).
  // Write-side transpose: Cs quarter [il 0..31][j' 0..127] f32; scalar writes
  // at phys slot (jp>>2)^il, elem jp&3; reads/stores are full-line f32x4.
  if (offdiag) {
#pragma unroll
    for (int qi = 0; qi < 4; ++qi) {
      if (wr == (qi >> 1)) {
#pragma unroll
        for (int mm = 0; mm < 2; ++mm) {
          const int m = (qi & 1) * 2 + mm;
#pragma unroll
          for (int n = 0; n < 4; ++n) {
            const int jp = wc * 64 + n * 16 + l16;     // j' 0..127
#pragma unroll
            for (int r = 0; r < 4; ++r) {
              const int il = mm * 16 + lhi * 4 + r;    // 0..31
              const float val = sqr[m][r] + sqc[n] - 2.0f * acc[m][n][r];
              *(float*)(smem + il * 512 + (((jp >> 2) ^ il) << 4) + (jp & 3) * 4) = val;
            }
          }
        }
      }
      barrier_lds_only();
      {
        const int irow0 = bi * 128 + qi * 32;
#pragma unroll
        for (int k = 0; k < 4; ++k) {
          const int idx = k * 256 + t;
          const int il = idx >> 5;
          const int s = idx & 31;
          f32x4 v = *(const f32x4*)(smem + il * 512 + ((s ^ il) << 4));
          __builtin_nontemporal_store(
              v, (f32x4*)&outg[(size_t)(irow0 + il) * NN + bj * 128 + s * 4]);
        }
      }
      if (qi < 3) barrier_lds_only();
    }
  }
}

extern "C" void kernel_launch(void* const* d_in, const int* in_sizes, int n_in,
                              void* d_out, int out_size, void* d_ws, size_t ws_size,
                              hipStream_t stream) {
  const float* h = (const float*)d_in[0];
  float* out = (float*)d_out;

  float* sq = (float*)d_ws;                                   // 32768 f32 = 128 KB
  unsigned short* hbf = (unsigned short*)((char*)d_ws + NROW * 4);  // 32 MB bf16
  const size_t need_ws = (size_t)NROW * 4 + (size_t)NROW * DD * 2;
  const bool use_ws = ws_size >= need_ws;

  if (use_ws) {
    prep_kernel<true><<<NROW / 4, 256, 0, stream>>>(h, hbf, sq);
    gram_kernel<true><<<NG * NPAIR, 256, 0, stream>>>(hbf, nullptr, sq, out);
  } else {
    prep_kernel<false><<<NROW / 4, 256, 0, stream>>>(h, nullptr, sq);
    gram_kernel<false><<<NG * NPAIR, 256, 0, stream>>>(nullptr, h, sq, out);
  }
}